// Round 1
// 144.590 us; speedup vs baseline: 1.0141x; 1.0141x over previous
//
#include <hip/hip_runtime.h>

// GeodesicLoss: reference's velocity starts at exactly zero, so
// acc = -einsum(Gamma, v, v) == 0 every step and traj == outputs identically.
// Answer = mean_b ||outputs[b] - targets[b]||_2, B=524288, D=32.
// christoffel_symbols (d_in[2]) is mathematically dead.
//
// R4 theory: VGPR_Count=32 proved the compiler again sank the hoisted loads
// (16 float4 need 64 VGPRs). Batched loads + full drains -> latency-bound at
// 3.1 TB/s effective. Fixes:
//  (a) sched_barrier(0) pins all 8 float4 loads/thread before first use
//      (8 KB MLP/wave), sized so VGPR stays <=64 -> full 32 waves/CU.
//  (b) per-wave partials -> d_ws + tiny finish kernel: removes the 2048-deep
//      same-address atomicAdd burst AND the hipMemsetAsync node.

static constexpr int B_ROWS       = 524288;
static constexpr int ROWS_PER_BLK = 128;                    // 256 threads, 4 f4-pairs each
static constexpr int NUM_BLOCKS   = B_ROWS / ROWS_PER_BLK;  // 4096
static constexpr int PAD          = 9;                      // LDS row stride (floats)
static constexpr int NUM_PARTIALS = NUM_BLOCKS * 2;         // 2 waves' sums per block

__global__ __launch_bounds__(256) void geodesic_main(
    const float4* __restrict__ o4,
    const float4* __restrict__ t4,
    float* __restrict__ ws)
{
    __shared__ float part[ROWS_PER_BLK * PAD];              // 4608 B
    const int t    = threadIdx.x;
    const int base = blockIdx.x * (ROWS_PER_BLK * 8);       // float4 index, fits int

    // 8 independent, perfectly coalesced 16B loads. sched_barrier(0) below
    // forbids the scheduler from sinking ANY of them past it: all 8 must be
    // in flight before the first use.
    float4 o[4], g[4];
#pragma unroll
    for (int k = 0; k < 4; ++k) {
        o[k] = o4[base + k * 256 + t];
        g[k] = t4[base + k * 256 + t];
    }
    __builtin_amdgcn_sched_barrier(0);

    // Per-float4 squared-diff partials -> LDS (row-major, pad 9:
    // writes 2-3-way bank aliased = ~free, reads 2-way = free, per m136).
    const int l8 = t & 7;
#pragma unroll
    for (int k = 0; k < 4; ++k) {
        float dx = o[k].x - g[k].x;
        float dy = o[k].y - g[k].y;
        float dz = o[k].z - g[k].z;
        float dw = o[k].w - g[k].w;
        float p  = dx * dx + dy * dy + dz * dz + dw * dw;
        const int rl = (k * 256 + t) >> 3;                  // local row 0..127
        part[rl * PAD + l8] = p;
    }
    __syncthreads();

    // Threads 0..127 own one row each: sum 8 partials, sqrt.
    // Waves 2,3 have no rows -> they exit after the barrier.
    if (t < ROWS_PER_BLK) {
        float ss = 0.0f;
#pragma unroll
        for (int j = 0; j < 8; ++j) ss += part[t * PAD + j];
        float d = sqrtf(ss);

        // 6-step wave reduce; waves 0,1 each store one partial. No atomics,
        // no second barrier: the finish kernel sums ws[0..8191].
        d += __shfl_xor(d, 1);
        d += __shfl_xor(d, 2);
        d += __shfl_xor(d, 4);
        d += __shfl_xor(d, 8);
        d += __shfl_xor(d, 16);
        d += __shfl_xor(d, 32);
        if ((t & 63) == 0) ws[blockIdx.x * 2 + (t >> 6)] = d;
    }
}

__global__ __launch_bounds__(256) void geodesic_finish(
    const float4* __restrict__ ws4,                         // 8192 floats = 2048 float4
    float* __restrict__ out)
{
    const int t = threadIdx.x;
    float s = 0.0f;
#pragma unroll
    for (int k = 0; k < 8; ++k) {
        float4 v = ws4[k * 256 + t];
        s += (v.x + v.y) + (v.z + v.w);
    }
    s += __shfl_xor(s, 1);
    s += __shfl_xor(s, 2);
    s += __shfl_xor(s, 4);
    s += __shfl_xor(s, 8);
    s += __shfl_xor(s, 16);
    s += __shfl_xor(s, 32);

    __shared__ float sm[4];
    if ((t & 63) == 0) sm[t >> 6] = s;
    __syncthreads();
    if (t == 0) {
        out[0] = ((sm[0] + sm[1]) + (sm[2] + sm[3])) * (1.0f / (float)B_ROWS);
    }
}

extern "C" void kernel_launch(void* const* d_in, const int* in_sizes, int n_in,
                              void* d_out, int out_size, void* d_ws, size_t ws_size,
                              hipStream_t stream) {
    const float4* outputs = (const float4*)d_in[0];
    const float4* targets = (const float4*)d_in[1];
    // d_in[2] (christoffel_symbols) unused: velocity is identically zero.
    float* ws  = (float*)d_ws;                              // 8192 floats (32 KiB)
    float* out = (float*)d_out;

    // No memset needed: geodesic_finish writes out[0] unconditionally
    // (d_out re-poison is overwritten every launch).
    geodesic_main<<<dim3(NUM_BLOCKS), dim3(256), 0, stream>>>(outputs, targets, ws);
    geodesic_finish<<<dim3(1), dim3(256), 0, stream>>>((const float4*)ws, out);
}